// Round 6
// baseline (173.151 us; speedup 1.0000x reference)
//
#include <hip/hip_runtime.h>
#include <hip/hip_bf16.h>
#include <hip/hip_cooperative_groups.h>

namespace cg = cooperative_groups;

// Single cooperative launch, whole pipeline. B=1024, IN=768, HID=512, OUT=256.
// Grid = driver-validated co-resident block count (occupancy query, <=512),
// all phases grid-stride so any grid size is correct.
//   Phase A: 1024 jobs: jobs 0..511 c = combin@W2^T+b2 (K=768);
//            512..1023  t = s_emb@W1^T+b1 (K=512).
//            One job per 256-thr HALF-BLOCK (4-wave K-split, direct global
//            fragment loads, parallel cross-wave reduce — r2-proven shape).
//   [grid.sync]
//   Phase B: 1024 batches, one per half-block: Taylor moments (64-lane
//            butterfly) + deg-7 Horner softmax-ratio + relu -> o2 bf16
//            (r0-proven math).
//   [grid.sync]
//   Phase C: 256 out-tiles (32x32, K=512) per block, 8-wave K-split
//            (r3-proven shape): out = o2@W3^T + b3.

#define B_SZ 1024
#define HID 512
#define IN_D 768
#define OUT_D 256
#define NK 8

typedef float floatx16 __attribute__((ext_vector_type(16)));
typedef short short8  __attribute__((ext_vector_type(8)));

// round-half-up fp32->bf16 pair pack (low16 = a, high16 = b)
__device__ __forceinline__ unsigned pack_bf16(float a, float b) {
    unsigned ua = __float_as_uint(a) + 0x8000u;
    unsigned ub = __float_as_uint(b) + 0x8000u;
    return __builtin_amdgcn_perm(ub, ua, 0x07060302);
}
__device__ __forceinline__ uint4 pack8(float4 lo, float4 hi) {
    uint4 v;
    v.x = pack_bf16(lo.x, lo.y); v.y = pack_bf16(lo.z, lo.w);
    v.z = pack_bf16(hi.x, hi.y); v.w = pack_bf16(hi.z, hi.w);
    return v;
}

// K-loop, fp32 inputs packed to bf16 on the fly; direct global fragment
// loads (m=lane&31 -> row, kh=lane>>5 -> 8-float half), depth-1 prefetch.
template<int NCH>
__device__ __forceinline__ floatx16 kloop_f32(
    const float* __restrict__ pa, const float* __restrict__ pw)
{
    float4 a0 = *(const float4*)pa, a1 = *(const float4*)(pa + 4);
    float4 b0 = *(const float4*)pw, b1 = *(const float4*)(pw + 4);
    floatx16 acc = {};
    #pragma unroll
    for (int c = 0; c < NCH; ++c) {
        uint4 af = pack8(a0, a1);
        uint4 bf = pack8(b0, b1);
        if (c + 1 < NCH) {
            pa += 16; pw += 16;
            a0 = *(const float4*)pa; a1 = *(const float4*)(pa + 4);
            b0 = *(const float4*)pw; b1 = *(const float4*)(pw + 4);
        }
        acc = __builtin_amdgcn_mfma_f32_32x32x16_bf16(
            *(short8*)&af, *(short8*)&bf, acc, 0, 0, 0);
    }
    return acc;
}

// K-loop, bf16 A / fp32 W
template<int NCH>
__device__ __forceinline__ floatx16 kloop_bf16(
    const __hip_bfloat16* __restrict__ pa, const float* __restrict__ pw)
{
    uint4 av = *(const uint4*)pa;
    float4 b0 = *(const float4*)pw, b1 = *(const float4*)(pw + 4);
    floatx16 acc = {};
    #pragma unroll
    for (int c = 0; c < NCH; ++c) {
        uint4 af = av;
        uint4 bf = pack8(b0, b1);
        if (c + 1 < NCH) {
            pa += 16; pw += 16;
            av = *(const uint4*)pa;
            b0 = *(const float4*)pw; b1 = *(const float4*)(pw + 4);
        }
        acc = __builtin_amdgcn_mfma_f32_32x32x16_bf16(
            *(short8*)&af, *(short8*)&bf, acc, 0, 0, 0);
    }
    return acc;
}

// 4-wave cross-K reduction + biased coalesced store into a [32][N] tile.
// redf is this half-block's private 16 KB slab. Whole-block barriers are
// safe: the enclosing branch is block-uniform and both halves call this
// at the same point. Trailing barrier covers WAR reuse across grid-stride
// iterations.
__device__ __forceinline__ void reduce_store(
    const floatx16& acc, float (*__restrict__ redf)[64],
    const float* __restrict__ bias, float* __restrict__ C, int N,
    int row0, int col0, int w, int lane, int m, int kh)
{
    #pragma unroll
    for (int q = 0; q < 16; ++q) redf[w * 16 + q][lane] = acc[q];
    __syncthreads();
    // C/D layout: col=lane&31, row=(q&3)+8*(q>>2)+4*kh; q=4w+i -> row=i+8w+4kh
    const float bv = bias[col0 + m];
    float* cb = C + (size_t)(row0 + 8 * w + 4 * kh) * N + col0 + m;
    #pragma unroll
    for (int i = 0; i < 4; ++i) {
        const int q = 4 * w + i;
        float s = redf[q][lane] + redf[16 + q][lane]
                + redf[32 + q][lane] + redf[48 + q][lane];
        cb[(size_t)i * N] = s + bv;          // 128B coalesced
    }
    __syncthreads();
}

__global__ __launch_bounds__(512, 4) void fused_all(
    const float* __restrict__ combin, const float* __restrict__ s_emb,
    const float* __restrict__ W1, const float* __restrict__ b1,
    const float* __restrict__ W2, const float* __restrict__ b2,
    const float* __restrict__ W3, const float* __restrict__ b3,
    float* __restrict__ c_emb, float* __restrict__ t_emb,
    unsigned* __restrict__ o2u, float* __restrict__ out)
{
    __shared__ float redf[2][64][64];         // 32 KB: two 16 KB half-slabs
    __shared__ float redp[2][4][2 * NK];      // 512 B

    cg::grid_group grid = cg::this_grid();

    const int tid  = threadIdx.x;             // 0..511
    const int h    = tid >> 8;                // half-block 0/1
    const int t2   = tid & 255;               // tid within half
    const int w4   = t2 >> 6;                 // wave within half 0..3
    const int lane = tid & 63;
    const int m    = lane & 31;
    const int kh   = lane >> 5;
    const int nb2  = gridDim.x * 2;

    // ================= Phase A: c and t GEMMs (1024 half-block jobs) =====
    for (int job = blockIdx.x * 2 + h; job < 1024; job += nb2) {
        if (job < 512) {                      // block-uniform (jobs paired)
            const int row0 = (job >> 4) * 32, col0 = (job & 15) * 32;
            const int k0 = w4 * 12 * 16 + kh * 8;
            floatx16 acc = kloop_f32<12>(
                combin + (size_t)(row0 + m) * IN_D + k0,
                W2     + (size_t)(col0 + m) * IN_D + k0);
            reduce_store(acc, redf[h], b2, c_emb, HID, row0, col0, w4, lane, m, kh);
        } else {
            const int j = job - 512;
            const int row0 = (j >> 4) * 32, col0 = (j & 15) * 32;
            const int k0 = w4 * 8 * 16 + kh * 8;
            floatx16 acc = kloop_f32<8>(
                s_emb + (size_t)(row0 + m) * HID + k0,
                W1    + (size_t)(col0 + m) * HID + k0);
            reduce_store(acc, redf[h], b1, t_emb, HID, row0, col0, w4, lane, m, kh);
        }
    }
    grid.sync();

    // ================= Phase B: Taylor attention (1024 half-block batches)
    for (int b = blockIdx.x * 2 + h; b < B_SZ; b += nb2) {
        const float2 tt = *(const float2*)(t_emb + (size_t)b * HID + 2 * t2);
        const float2 vv = *(const float2*)(s_emb + (size_t)b * HID + 2 * t2);
        const float2 cc = *(const float2*)(c_emb + (size_t)b * HID + 2 * t2);

        float val[2 * NK];
        float tp0 = 1.f, tp1 = 1.f;
        #pragma unroll
        for (int k = 0; k < NK; ++k) {
            val[k]      = tp0 + tp1;                   // p_k partial (2 j's)
            val[NK + k] = fmaf(tp0, vv.x, tp1 * vv.y); // m_k partial
            tp0 *= tt.x; tp1 *= tt.y;
        }
        #pragma unroll
        for (int off = 1; off < 64; off <<= 1)
            #pragma unroll
            for (int k = 0; k < 2 * NK; ++k)
                val[k] += __shfl_xor(val[k], off);
        if (lane == 0)
            #pragma unroll
            for (int k = 0; k < 2 * NK; ++k) redp[h][w4][k] = val[k];
        __syncthreads();

        const float invf[NK] = {1.f, 1.f, 0.5f, 1.f / 6.f, 1.f / 24.f,
                                1.f / 120.f, 1.f / 720.f, 1.f / 5040.f};
        float cp[NK], cm[NK];
        #pragma unroll
        for (int k = 0; k < NK; ++k) {        // broadcast LDS reads (free)
            cp[k] = (redp[h][0][k] + redp[h][1][k]
                   + redp[h][2][k] + redp[h][3][k]) * invf[k];
            cm[k] = (redp[h][0][NK + k] + redp[h][1][NK + k]
                   + redp[h][2][NK + k] + redp[h][3][NK + k]) * invf[k];
        }

        const float scale = 0.04419417382415922f;  // 1/sqrt(512)
        const float a0 = scale * cc.x, a1 = scale * cc.y;
        float n0 = cm[NK - 1], d0 = cp[NK - 1];
        float n1 = cm[NK - 1], d1 = cp[NK - 1];
        #pragma unroll
        for (int k = NK - 2; k >= 0; --k) {
            n0 = fmaf(n0, a0, cm[k]); d0 = fmaf(d0, a0, cp[k]);
            n1 = fmaf(n1, a1, cm[k]); d1 = fmaf(d1, a1, cp[k]);
        }
        float r0v = n0 * __builtin_amdgcn_rcpf(d0);
        float r1v = n1 * __builtin_amdgcn_rcpf(d1);
        r0v = r0v > 0.f ? r0v : 0.f;
        r1v = r1v > 0.f ? r1v : 0.f;
        o2u[(size_t)b * (HID / 2) + t2] = pack_bf16(r0v, r1v);  // coalesced
        __syncthreads();                      // WAR on redp across iterations
    }
    grid.sync();

    // ================= Phase C: out-GEMM, 256 tiles, 8-wave K-split ======
    for (int tile = blockIdx.x; tile < 256; tile += gridDim.x) {
        const int w8 = tid >> 6;              // 0..7
        const int row0 = (tile >> 3) * 32, col0 = (tile & 7) * 32;
        const int k0 = w8 * 64 + kh * 8;
        floatx16 acc = kloop_bf16<4>(
            (const __hip_bfloat16*)o2u + (size_t)(row0 + m) * HID + k0,
            W3 + (size_t)(col0 + m) * HID + k0);

        float* rf = &redf[0][0][0];           // 32 KB flat: [128][64]
        #pragma unroll
        for (int q = 0; q < 16; ++q) rf[(w8 * 16 + q) * 64 + lane] = acc[q];
        __syncthreads();

        // wave w8 reduces q = 2w8, 2w8+1 over 8 partials; coalesced stores
        const float bv = b3[col0 + m];
        #pragma unroll
        for (int i = 0; i < 2; ++i) {
            const int q = 2 * w8 + i;
            float s = 0.f;
            #pragma unroll
            for (int ww = 0; ww < 8; ++ww) s += rf[(ww * 16 + q) * 64 + lane];
            const int rr = (q & 3) + 8 * (q >> 2) + 4 * kh;
            out[(size_t)(row0 + rr) * OUT_D + col0 + m] = s + bv;
        }
        __syncthreads();                      // WAR on rf across iterations
    }
}

extern "C" void kernel_launch(void* const* d_in, const int* in_sizes, int n_in,
                              void* d_out, int out_size, void* d_ws, size_t ws_size,
                              hipStream_t stream)
{
    const float* combin = (const float*)d_in[0];
    const float* s_emb  = (const float*)d_in[1];
    const float* W1     = (const float*)d_in[2];
    const float* b1     = (const float*)d_in[3];
    const float* W2     = (const float*)d_in[4];
    const float* b2     = (const float*)d_in[5];
    const float* W3     = (const float*)d_in[6];
    const float* b3     = (const float*)d_in[7];
    float* out = (float*)d_out;

    float* ws = (float*)d_ws;
    float*    c_emb = ws;                                        // 2 MB
    float*    t_emb = ws + (size_t)B_SZ * HID;                   // 2 MB
    unsigned* o2u   = (unsigned*)(ws + (size_t)2 * B_SZ * HID);  // 1 MB

    // Grid = driver-validated co-resident capacity (cached; pure queries,
    // no stream ops -> graph-capture-safe). Grid-stride phases make any
    // value correct; cap at 512 (= 2 half-block jobs per block minimum).
    static int nblk = 0;
    if (nblk == 0) {
        int occ = 0, cu = 256;
        hipOccupancyMaxActiveBlocksPerMultiprocessor(
            &occ, (const void*)fused_all, 512, 0);
        hipDeviceProp_t prop;
        if (hipGetDeviceProperties(&prop, 0) == hipSuccess &&
            prop.multiProcessorCount > 0)
            cu = prop.multiProcessorCount;
        if (occ < 1) occ = 1;
        long cap = (long)occ * cu;
        nblk = cap > 512 ? 512 : (int)cap;
        if (nblk < 1) nblk = 1;
    }

    void* args[] = {(void*)&combin, (void*)&s_emb, (void*)&W1, (void*)&b1,
                    (void*)&W2, (void*)&b2, (void*)&W3, (void*)&b3,
                    (void*)&c_emb, (void*)&t_emb, (void*)&o2u, (void*)&out};
    hipLaunchCooperativeKernel((const void*)fused_all, dim3(nblk), dim3(512),
                               args, 0, stream);
}

// Round 7
// 98.262 us; speedup vs baseline: 1.7621x; 1.7621x over previous
//
#include <hip/hip_runtime.h>
#include <hip/hip_bf16.h>

// B=1024, IN=768, HID=512, OUT=256  (r0 structure — best measured: 93.6 µs)
//   c = combin @ W2^T + b2   [1024,512] K=768   (bf16 MFMA)
//   t = s_emb  @ W1^T + b1   [1024,512] K=512   (bf16 MFMA, fused launch)
//   o2[b,i] = relu(Taylor-softmax ratio)        (moments trick, deg-7)
//   out = o2 @ W3^T + b3     [1024,256] K=512
//
// GEMM: 32x32 tile/block, 4 waves each owning a K-slice with private LDS
// staging -> NO barrier in the K-loop (same-wave DS ops are program-ordered);
// 1024 blocks = 4 waves/SIMD hide each other's latency. One barrier + LDS
// reduce of 4 partials at end.  [r0-verbatim]
// attn: butterfly-shuffle moments (r6-Phase-B-verified math): 96 shfl_xor +
// 256 B LDS + 2 barriers, replacing r0's 17 KB part-array walk + 4 barriers.

#define B_SZ 1024
#define HID 512
#define IN_D 768
#define OUT_D 256
#define NK 8

typedef float floatx16 __attribute__((ext_vector_type(16)));
typedef short short8  __attribute__((ext_vector_type(8)));

// round-half-up fp32->bf16 pair pack
__device__ __forceinline__ unsigned pack_bf16(float a, float b) {
    unsigned ua = __float_as_uint(a) + 0x8000u;
    unsigned ub = __float_as_uint(b) + 0x8000u;
    return __builtin_amdgcn_perm(ub, ua, 0x07060302);
}
__device__ __forceinline__ uint4 pack8(float4 lo, float4 hi) {
    uint4 v;
    v.x = pack_bf16(lo.x, lo.y); v.y = pack_bf16(lo.z, lo.w);
    v.z = pack_bf16(hi.x, hi.y); v.w = pack_bf16(hi.z, hi.w);
    return v;
}

// One 32x32 C tile. 4 waves split K (nch 16-wide chunks each). Per-wave LDS
// staging (A 1KB + B 1KB); lane L stages row L>>1, k-half L&1 -> index L.
// Fragment read: row m=lane&31, k-half kh=lane>>5 -> index m*2+kh.
template<bool A_BF16>
__device__ __forceinline__ void gemm32_tile(
    const void* Aip, const float* __restrict__ Wp,
    const float* __restrict__ bias, float* __restrict__ C,
    int N, int K, int nch, int row0, int col0,
    uint4 (*stage)[128], float (*redf)[64])   // redf[3*16][64]
{
    const int tid  = threadIdx.x;
    const int w    = tid >> 6;
    const int lane = tid & 63;
    const int r    = lane >> 1;
    const int h    = lane & 1;
    const int m    = lane & 31;
    const int kh   = lane >> 5;
    const int k0   = w * nch * 16;

    uint4* As = &stage[w][0];
    uint4* Bs = &stage[w][64];
    const uint4* fa = &stage[w][m * 2 + kh];
    const uint4* fb = &stage[w][64 + m * 2 + kh];

    const float* pw = Wp + (size_t)(col0 + r) * K + k0 + h * 8;

    floatx16 acc = {};

    if (A_BF16) {
        const __hip_bfloat16* Ab = (const __hip_bfloat16*)Aip;
        const __hip_bfloat16* pa = Ab + (size_t)(row0 + r) * K + k0 + h * 8;
        uint4 av = *(const uint4*)pa;
        float4 b0 = *(const float4*)pw, b1 = *(const float4*)(pw + 4);
        for (int c = 0; c < nch; ++c) {
            As[lane] = av;
            Bs[lane] = pack8(b0, b1);
            if (c + 1 < nch) {
                pa += 16; pw += 16;
                av = *(const uint4*)pa;
                b0 = *(const float4*)pw; b1 = *(const float4*)(pw + 4);
            }
            uint4 a4 = *fa, b4 = *fb;
            acc = __builtin_amdgcn_mfma_f32_32x32x16_bf16(
                *(short8*)&a4, *(short8*)&b4, acc, 0, 0, 0);
        }
    } else {
        const float* Af = (const float*)Aip;
        const float* pa = Af + (size_t)(row0 + r) * K + k0 + h * 8;
        float4 a0 = *(const float4*)pa, a1 = *(const float4*)(pa + 4);
        float4 b0 = *(const float4*)pw, b1 = *(const float4*)(pw + 4);
        for (int c = 0; c < nch; ++c) {
            As[lane] = pack8(a0, a1);
            Bs[lane] = pack8(b0, b1);
            if (c + 1 < nch) {
                pa += 16; pw += 16;
                a0 = *(const float4*)pa; a1 = *(const float4*)(pa + 4);
                b0 = *(const float4*)pw; b1 = *(const float4*)(pw + 4);
            }
            uint4 a4 = *fa, b4 = *fb;
            acc = __builtin_amdgcn_mfma_f32_32x32x16_bf16(
                *(short8*)&a4, *(short8*)&b4, acc, 0, 0, 0);
        }
    }

    // cross-wave K reduction: waves 1-3 dump, wave 0 reduces + stores.
    if (w > 0) {
        #pragma unroll
        for (int q = 0; q < 16; ++q) redf[(w - 1) * 16 + q][lane] = acc[q];
    }
    __syncthreads();
    if (w == 0) {
        #pragma unroll
        for (int s = 0; s < 3; ++s)
            #pragma unroll
            for (int q = 0; q < 16; ++q) acc[q] += redf[s * 16 + q][lane];
        // C/D layout (m74/m101): col=lane&31, row=(reg&3)+8*(reg>>2)+4*(lane>>5)
        const int ccol = col0 + m;
        const float bv = bias[ccol];
        float* cb = C + (size_t)row0 * N + ccol;
        #pragma unroll
        for (int q = 0; q < 16; ++q) {
            int rr = (q & 3) + 8 * (q >> 2) + 4 * kh;
            cb[(size_t)rr * N] = acc[q] + bv;
        }
    }
}

// fused c & t: blocks 0..511 -> c (K=768, 12 chunks/wave), 512..1023 -> t (8)
__global__ __launch_bounds__(256) void gemm_ct_k(
    const float* __restrict__ combin, const float* __restrict__ W2,
    const float* __restrict__ b2, float* __restrict__ c_emb,
    const float* __restrict__ s_emb, const float* __restrict__ W1,
    const float* __restrict__ b1, float* __restrict__ t_emb)
{
    __shared__ uint4 stage[4][128];
    __shared__ float redf[48][64];
    int id = blockIdx.x;
    if (id < 512) {
        gemm32_tile<false>(combin, W2, b2, c_emb, HID, IN_D, 12,
                           (id >> 4) * 32, (id & 15) * 32, stage, redf);
    } else {
        id -= 512;
        gemm32_tile<false>(s_emb, W1, b1, t_emb, HID, HID, 8,
                           (id >> 4) * 32, (id & 15) * 32, stage, redf);
    }
}

// out = o2(bf16) @ W3^T + b3 : 256 blocks (32 m x 8 n), K=512 -> 8 chunks/wave
__global__ __launch_bounds__(256) void gemm_out_k(
    const __hip_bfloat16* __restrict__ o2, const float* __restrict__ W3,
    const float* __restrict__ b3, float* __restrict__ out)
{
    __shared__ uint4 stage[4][128];
    __shared__ float redf[48][64];
    int id = blockIdx.x;
    gemm32_tile<true>(o2, W3, b3, out, OUT_D, HID, 8,
                      (id >> 3) * 32, (id & 7) * 32, stage, redf);
}

// Taylor attention, lean: one block per batch. Per-thread partial moments
// over its 2 cols, 64-lane shfl_xor butterfly, cross-wave via 256 B LDS,
// then per-thread deg-7 Horner. (math identical to r0; verified in r6-B)
__global__ __launch_bounds__(256) void attn_taylor(
    const float* __restrict__ c_emb, const float* __restrict__ t_emb,
    const float* __restrict__ s_emb, unsigned* __restrict__ o2u)
{
    __shared__ float redp[4][2 * NK];

    const int b = blockIdx.x, tid = threadIdx.x;
    const int w = tid >> 6, lane = tid & 63;

    const float2 tt = *(const float2*)(t_emb + (size_t)b * HID + 2 * tid);
    const float2 vv = *(const float2*)(s_emb + (size_t)b * HID + 2 * tid);
    const float2 cc = *(const float2*)(c_emb + (size_t)b * HID + 2 * tid);

    float val[2 * NK];
    float tp0 = 1.f, tp1 = 1.f;
    #pragma unroll
    for (int k = 0; k < NK; ++k) {
        val[k]      = tp0 + tp1;                    // p_k partial (2 j's)
        val[NK + k] = fmaf(tp0, vv.x, tp1 * vv.y);  // m_k partial
        tp0 *= tt.x; tp1 *= tt.y;
    }
    #pragma unroll
    for (int off = 1; off < 64; off <<= 1)
        #pragma unroll
        for (int k = 0; k < 2 * NK; ++k)
            val[k] += __shfl_xor(val[k], off);
    if (lane == 0)
        #pragma unroll
        for (int k = 0; k < 2 * NK; ++k) redp[w][k] = val[k];
    __syncthreads();

    const float invf[NK] = {1.f, 1.f, 0.5f, 1.f / 6.f, 1.f / 24.f,
                            1.f / 120.f, 1.f / 720.f, 1.f / 5040.f};
    float cp[NK], cm[NK];
    #pragma unroll
    for (int k = 0; k < NK; ++k) {                  // broadcast LDS reads
        cp[k] = (redp[0][k] + redp[1][k] + redp[2][k] + redp[3][k]) * invf[k];
        cm[k] = (redp[0][NK + k] + redp[1][NK + k]
               + redp[2][NK + k] + redp[3][NK + k]) * invf[k];
    }

    const float scale = 0.04419417382415922f;       // 1/sqrt(512)
    const float a0 = scale * cc.x, a1 = scale * cc.y;
    float n0 = cm[NK - 1], d0 = cp[NK - 1];
    float n1 = cm[NK - 1], d1 = cp[NK - 1];
    #pragma unroll
    for (int k = NK - 2; k >= 0; --k) {
        n0 = fmaf(n0, a0, cm[k]); d0 = fmaf(d0, a0, cp[k]);
        n1 = fmaf(n1, a1, cm[k]); d1 = fmaf(d1, a1, cp[k]);
    }
    float r0 = n0 * __builtin_amdgcn_rcpf(d0);
    float r1 = n1 * __builtin_amdgcn_rcpf(d1);
    r0 = r0 > 0.f ? r0 : 0.f;
    r1 = r1 > 0.f ? r1 : 0.f;
    // rows 2*tid, 2*tid+1 -> one packed dword, coalesced
    o2u[(size_t)b * (HID / 2) + tid] = pack_bf16(r0, r1);
}

extern "C" void kernel_launch(void* const* d_in, const int* in_sizes, int n_in,
                              void* d_out, int out_size, void* d_ws, size_t ws_size,
                              hipStream_t stream)
{
    const float* combin = (const float*)d_in[0];
    const float* s_emb  = (const float*)d_in[1];
    const float* W1     = (const float*)d_in[2];
    const float* b1     = (const float*)d_in[3];
    const float* W2     = (const float*)d_in[4];
    const float* b2     = (const float*)d_in[5];
    const float* W3     = (const float*)d_in[6];
    const float* b3     = (const float*)d_in[7];
    float* out = (float*)d_out;

    float* ws = (float*)d_ws;
    float* c_emb = ws;                            // [B, HID] fp32
    float* t_emb = ws + (size_t)B_SZ * HID;       // [B, HID] fp32
    unsigned* o2u = (unsigned*)(ws + (size_t)2 * B_SZ * HID);  // [B, HID] bf16

    gemm_ct_k<<<1024, 256, 0, stream>>>(combin, W2, b2, c_emb, s_emb, W1, b1, t_emb);
    attn_taylor<<<B_SZ, 256, 0, stream>>>(c_emb, t_emb, s_emb, o2u);
    gemm_out_k<<<256, 256, 0, stream>>>((const __hip_bfloat16*)o2u, W3, b3, out);
}